// Round 8
// baseline (427.492 us; speedup 1.0000x reference)
//
#include <hip/hip_runtime.h>
#include <hip/hip_bf16.h>

// LlamaAttention: B=2, T=2048, C=2048, H=16, D=128, rope theta 1e4, causal.
// Pipeline: fused cast->bf16, fused QKV GEMM (256^2 4-phase, all-at-ph0
// staging, rope+scale fused in epilogue with interleaved-d layout),
// flash attn, out proj GEMM (256x128 2-phase, 256 blocks).

typedef __attribute__((ext_vector_type(4))) float f32x4;
typedef __attribute__((ext_vector_type(8))) short s16x8;
typedef __attribute__((ext_vector_type(4))) short s16x4;

typedef void __attribute__((address_space(1))) gvoid;
typedef void __attribute__((address_space(3))) svoid;
#define ASYNC16(ldsp, gp) __builtin_amdgcn_global_load_lds((gvoid*)(gp), (svoid*)(ldsp), 16, 0, 0)
#define VMW(N) asm volatile("s_waitcnt vmcnt(" #N ")" ::: "memory")

__device__ __forceinline__ float bf2f(short b) {
  unsigned u = ((unsigned)(unsigned short)b) << 16;
  float f; __builtin_memcpy(&f, &u, 4); return f;
}
__device__ __forceinline__ short f2bf(float f) {
  unsigned u; __builtin_memcpy(&u, &f, 4);
  u += 0x7FFFu + ((u >> 16) & 1u);   // RTNE
  return (short)(u >> 16);
}

__device__ __forceinline__ f32x4 mfma16(s16x8 a, s16x8 b, f32x4 c) {
  return __builtin_amdgcn_mfma_f32_16x16x32_bf16(a, b, c, 0, 0, 0);
}

// ---------------- fused cast fp32 -> bf16 (x + 4 weights, one launch) -------
__global__ __launch_bounds__(256)
void cvt_all_k(const float* __restrict__ x,
               const float* __restrict__ w0, const float* __restrict__ w1,
               const float* __restrict__ w2, const float* __restrict__ w3,
               short* __restrict__ xb,
               short* __restrict__ o0, short* __restrict__ o1,
               short* __restrict__ o2, short* __restrict__ o3) {
  int i = blockIdx.x * 256 + threadIdx.x;   // [0, 2097152 + 4*1048576)
  const float* in; short* out; int j;
  if (i < 2097152) { in = x; out = xb; j = i; }
  else {
    int k2 = i - 2097152; int sel = k2 >> 20; j = k2 & 1048575;
    in  = (sel == 0) ? w0 : (sel == 1) ? w1 : (sel == 2) ? w2 : w3;
    out = (sel == 0) ? o0 : (sel == 1) ? o1 : (sel == 2) ? o2 : o3;
  }
  f32x4 v = *(const f32x4*)&in[j * 4];
  s16x4 o;
#pragma unroll
  for (int e = 0; e < 4; e++) o[e] = f2bf(v[e]);
  *(s16x4*)&out[j * 4] = o;
}

// ---------------- rope tables, [j 64][t 2048] layout ----------------
__global__ __launch_bounds__(256)
void rope_tables_k(float* __restrict__ cosT, float* __restrict__ sinT) {
  int id = blockIdx.x * 256 + threadIdx.x;  // 131072
  int j = id >> 11, t = id & 2047;
  float inv = exp2f(-(float)j * 0.20762050593046f); // 10000^(-j/64)
  float a = (float)t * inv;
  cosT[j * 2048 + t] = cosf(a);
  sinT[j * 2048 + t] = sinf(a);
}

// ---------------- QKV GEMM: 256x256, BK=64, 4-phase, rope epilogue ---------
// LDS layout (round-5 proven, 0 conflicts): [buf][256 rows][64 k], 128B rows,
// granule-XOR swizzle g^(row&7), inverse-swizzled global source.
// Stage schedule: ph0: A1,B0,B1(t+1) -> buf^1 (6 loads, 4-phase lead);
// ph3: A0(t+2) -> buf p (region free after ph2) + vmcnt(2).
// q/k outputs stored in interleaved-d layout (pairs (j,j+64) adjacent);
// rope + scale applied in epilogue via shfl_xor(.,1).
__global__ __launch_bounds__(512, 1)
void gemm_qkv9_k(const short* __restrict__ A,
                 const short* __restrict__ Bq, const short* __restrict__ Bk,
                 const short* __restrict__ Bv,
                 short* __restrict__ Cq, short* __restrict__ Ck,
                 short* __restrict__ Cv,
                 const float* __restrict__ cosT, const float* __restrict__ sinT) {
  const int K = 2048, NT = 32;
  __shared__ short As[2 * 16384];
  __shared__ short Bs[2 * 16384];
  const int tid = threadIdx.x;
  const int wid = tid >> 6, lane = tid & 63;
  const int lr = lane & 15, lk = lane >> 4;
  const int wr = wid >> 2, wc = wid & 3;       // 2M x 4N waves
  const int sel = blockIdx.x >> 3;
  const int n0 = (blockIdx.x & 7) * 256;
  const int m0 = blockIdx.y * 256;
  const short* B = (sel == 0) ? Bq : (sel == 1) ? Bk : Bv;
  short* C = (sel == 0) ? Cq : (sel == 1) ? Ck : Cv;
  const int rope = (sel < 2);

  // staging geometry (r5-proven): thread covers granules lin0, lin1 per half
  const int lin0 = wid * 128 + lane;
  const int lin1 = wid * 128 + 64 + lane;
  const int r0 = lin0 >> 3, r1 = lin1 >> 3;
  const int kk0 = ((lin0 & 7) ^ (r0 & 7)) * 8;   // inverse-swizzled source k
  const int kk1 = ((lin1 & 7) ^ (r1 & 7)) * 8;
  // permuted B rows for q/k (interleave (j, j+64) pairs within each head)
  auto permrow = [&](int sr) -> int {
    if (!rope) return sr;
    int u = sr & 127;
    return (sr & ~127) | ((u & 1) << 6) | (u >> 1);
  };

  f32x4 acc[8][4] = {};

#define STAGE_A(buf, h, t)                                                     \
  { ASYNC16(&As[(buf)*16384 + (h)*8192 + lin0*8],                              \
            A + (long)(m0 + (h)*128 + r0) * K + (t)*64 + kk0);                 \
    ASYNC16(&As[(buf)*16384 + (h)*8192 + lin1*8],                              \
            A + (long)(m0 + (h)*128 + r1) * K + (t)*64 + kk1); }
#define STAGE_B(buf, h, t)                                                     \
  { ASYNC16(&Bs[(buf)*16384 + (h)*8192 + lin0*8],                              \
            B + (long)(n0 + permrow((h)*128 + r0)) * K + (t)*64 + kk0);        \
    ASYNC16(&Bs[(buf)*16384 + (h)*8192 + lin1*8],                              \
            B + (long)(n0 + permrow((h)*128 + r1)) * K + (t)*64 + kk1); }
#define LDA(mi, ks) (*(const s16x8*)&As[p*16384 +                              \
    (wr*128 + (mi)*16 + lr)*64 + (((ks)*4 + lk) ^ (lr & 7))*8])
#define LDB(ni, ks) (*(const s16x8*)&Bs[p*16384 +                              \
    (wc*64 + (ni)*16 + lr)*64 + (((ks)*4 + lk) ^ (lr & 7))*8])

  // ---- prologue: tile0 complete + tile1.A0 in flight ----
  STAGE_A(0, 0, 0); STAGE_A(0, 1, 0);
  STAGE_B(0, 0, 0); STAGE_B(0, 1, 0);
  STAGE_A(1, 0, 1);
  VMW(2);
  __builtin_amdgcn_sched_barrier(0);
  __builtin_amdgcn_s_barrier();

  for (int t = 0; t < NT; ++t) {
    const int p = t & 1;
    const bool s1 = (t + 1 < NT), s2 = (t + 2 < NT);
    s16x8 af[8], b0, b1;
    // ---- ph0: ks0 x n{0,1}; stage ALL of t+1's free-buffer chunks ----
#pragma unroll
    for (int mi = 0; mi < 8; mi++) af[mi] = LDA(mi, 0);
    b0 = LDB(0, 0); b1 = LDB(1, 0);
    if (s1) { STAGE_A(p ^ 1, 1, t + 1); STAGE_B(p ^ 1, 0, t + 1); STAGE_B(p ^ 1, 1, t + 1); }
    __builtin_amdgcn_s_barrier();
    __builtin_amdgcn_s_setprio(1);
#pragma unroll
    for (int mi = 0; mi < 8; mi++) {
      acc[mi][0] = mfma16(af[mi], b0, acc[mi][0]);
      acc[mi][1] = mfma16(af[mi], b1, acc[mi][1]);
    }
    __builtin_amdgcn_s_setprio(0);
    __builtin_amdgcn_s_barrier();
    // ---- ph1: ks0 x n{2,3} ----
    b0 = LDB(2, 0); b1 = LDB(3, 0);
    __builtin_amdgcn_s_barrier();
    __builtin_amdgcn_s_setprio(1);
#pragma unroll
    for (int mi = 0; mi < 8; mi++) {
      acc[mi][2] = mfma16(af[mi], b0, acc[mi][2]);
      acc[mi][3] = mfma16(af[mi], b1, acc[mi][3]);
    }
    __builtin_amdgcn_s_setprio(0);
    __builtin_amdgcn_s_barrier();
    // ---- ph2: ks1 x n{0,1} ----
#pragma unroll
    for (int mi = 0; mi < 8; mi++) af[mi] = LDA(mi, 1);
    b0 = LDB(0, 1); b1 = LDB(1, 1);
    __builtin_amdgcn_s_barrier();
    __builtin_amdgcn_s_setprio(1);
#pragma unroll
    for (int mi = 0; mi < 8; mi++) {
      acc[mi][0] = mfma16(af[mi], b0, acc[mi][0]);
      acc[mi][1] = mfma16(af[mi], b1, acc[mi][1]);
    }
    __builtin_amdgcn_s_setprio(0);
    __builtin_amdgcn_s_barrier();
    // ---- ph3: ks1 x n{2,3} + cross-tile A0(t+2) + counted vmcnt ----
    b0 = LDB(2, 1); b1 = LDB(3, 1);
    if (s2) {
      STAGE_A(p, 0, t + 2);
      VMW(2);                 // forces all of t+1 (issued 4 phases ago)
    } else {
      VMW(0);
    }
    __builtin_amdgcn_sched_barrier(0);
    __builtin_amdgcn_s_barrier();
    __builtin_amdgcn_s_setprio(1);
#pragma unroll
    for (int mi = 0; mi < 8; mi++) {
      acc[mi][2] = mfma16(af[mi], b0, acc[mi][2]);
      acc[mi][3] = mfma16(af[mi], b1, acc[mi][3]);
    }
    __builtin_amdgcn_s_setprio(0);
    __builtin_amdgcn_s_barrier();
  }
  VMW(0);
  // ---- epilogue: rope (+scale for q) in interleaved-d layout ----
  const float qscale = (sel == 0) ? 0.08838834764831845f : 1.0f;
#pragma unroll
  for (int mi = 0; mi < 8; mi++) {
    const int rowb = m0 + wr * 128 + mi * 16 + lk * 4;
    const int t0 = rowb & 2047;
#pragma unroll
    for (int ni = 0; ni < 4; ni++) {
      const int col = n0 + wc * 64 + ni * 16 + lr;
      if (rope) {
        const int j = (wc & 1) * 32 + ni * 8 + (lr >> 1);
        f32x4 cc = *(const f32x4*)&cosT[j * 2048 + t0];
        f32x4 sn = *(const f32x4*)&sinT[j * 2048 + t0];
#pragma unroll
        for (int r = 0; r < 4; r++) {
          float a = acc[mi][ni][r];
          float bpart = __shfl_xor(a, 1);
          float v = (lr & 1) ? (a * cc[r] + bpart * sn[r])
                             : (a * cc[r] - bpart * sn[r]);
          C[(long)(rowb + r) * 2048 + col] = f2bf(v * qscale);
        }
      } else {
#pragma unroll
        for (int r = 0; r < 4; r++)
          C[(long)(rowb + r) * 2048 + col] = f2bf(acc[mi][ni][r]);
      }
    }
  }
#undef STAGE_A
#undef STAGE_B
#undef LDA
#undef LDB
}

// ---------------- out GEMM: 256x128, BK=64, 2 phases, 256 blocks ----------
// 8 waves 4M x 2N (wave tile 64x64). LDS 96KB: As[2][256][64], Bs[2][128][64].
// FIX(r8): full staging — 4 A-granules + 2 B-granules per thread
// (256 rows x 8 granules A = 2048, 128 x 8 B = 1024; 512 threads).
__global__ __launch_bounds__(512, 1)
void gemm_out9_k(const short* __restrict__ A, const short* __restrict__ Bw,
                 float* __restrict__ C) {
  const int K = 2048, NT = 32;
  __shared__ short As[2 * 16384];
  __shared__ short Bs[2 * 8192];
  const int tid = threadIdx.x;
  const int wid = tid >> 6, lane = tid & 63;
  const int lr = lane & 15, lk = lane >> 4;
  const int wr = wid >> 1, wc = wid & 1;          // 4M x 2N waves
  const int n0 = blockIdx.x * 128;
  const int m0 = blockIdx.y * 256;
  const short* PA = A + (long)m0 * K;
  const short* PB = Bw + (long)n0 * K;

  f32x4 acc[4][4] = {};

  auto STGO = [&](int buf, int t) {
    const long kof = (long)t * 64;
#pragma unroll
    for (int i = 0; i < 4; i++) {
      int g = tid + 512 * i, rr = g >> 3;
      int kk2 = ((g & 7) ^ (rr & 7)) * 8;
      ASYNC16(&As[buf * 16384 + g * 8], PA + (long)rr * K + kof + kk2);
    }
#pragma unroll
    for (int i = 0; i < 2; i++) {
      int g = tid + 512 * i, rr = g >> 3;
      int kk2 = ((g & 7) ^ (rr & 7)) * 8;
      ASYNC16(&Bs[buf * 8192 + g * 8], PB + (long)rr * K + kof + kk2);
    }
  };
#define LDAO(mi, ks) (*(const s16x8*)&As[p*16384 +                             \
    (wr*64 + (mi)*16 + lr)*64 + (((ks)*4 + lk) ^ (lr & 7))*8])
#define LDBO(ni, ks) (*(const s16x8*)&Bs[p*8192 +                              \
    (wc*64 + (ni)*16 + lr)*64 + (((ks)*4 + lk) ^ (lr & 7))*8])

  STGO(0, 0);
  VMW(0);
  __builtin_amdgcn_sched_barrier(0);
  __builtin_amdgcn_s_barrier();

  for (int t = 0; t < NT; ++t) {
    const int p = t & 1;
    const bool s1 = (t + 1 < NT);
    s16x8 af[4], bf[4];
    // ---- ph0: ks0 (stage all of t+1) ----
#pragma unroll
    for (int mi = 0; mi < 4; mi++) af[mi] = LDAO(mi, 0);
#pragma unroll
    for (int ni = 0; ni < 4; ni++) bf[ni] = LDBO(ni, 0);
    if (s1) STGO(p ^ 1, t + 1);
    __builtin_amdgcn_s_barrier();
    __builtin_amdgcn_s_setprio(1);
#pragma unroll
    for (int mi = 0; mi < 4; mi++)
#pragma unroll
      for (int ni = 0; ni < 4; ni++)
        acc[mi][ni] = mfma16(af[mi], bf[ni], acc[mi][ni]);
    __builtin_amdgcn_s_setprio(0);
    __builtin_amdgcn_s_barrier();
    // ---- ph1: ks1 + drain t+1's stages ----
#pragma unroll
    for (int mi = 0; mi < 4; mi++) af[mi] = LDAO(mi, 1);
#pragma unroll
    for (int ni = 0; ni < 4; ni++) bf[ni] = LDBO(ni, 1);
    __builtin_amdgcn_s_barrier();
    __builtin_amdgcn_s_setprio(1);
#pragma unroll
    for (int mi = 0; mi < 4; mi++)
#pragma unroll
      for (int ni = 0; ni < 4; ni++)
        acc[mi][ni] = mfma16(af[mi], bf[ni], acc[mi][ni]);
    __builtin_amdgcn_s_setprio(0);
    VMW(0);
    __builtin_amdgcn_sched_barrier(0);
    __builtin_amdgcn_s_barrier();
  }
#pragma unroll
  for (int mi = 0; mi < 4; mi++)
#pragma unroll
    for (int ni = 0; ni < 4; ni++)
#pragma unroll
      for (int r = 0; r < 4; r++) {
        int row = m0 + wr * 64 + mi * 16 + lk * 4 + r;
        int col = n0 + wc * 64 + ni * 16 + lr;
        C[(long)row * 2048 + col] = acc[mi][ni][r];
      }
#undef LDAO
#undef LDBO
}

// ---------------- flash attention (r4-proven; q pre-scaled, no scale mult) --
__global__ __launch_bounds__(256)
void attn_k(const short* __restrict__ q, const short* __restrict__ k,
            const short* __restrict__ v, short* __restrict__ o) {
  __shared__ short Ks[2][64 * 128];   // 32 KB, XOR-swizzled rows
  __shared__ short Vt[128 * 72];      // 18 KB, V^T padded stride 72
  __shared__ short Pl[4][16 * 72];    // 9 KB, per-wave P tile (stride 72)
  const int tid = threadIdx.x;
  const int wave = tid >> 6, lane = tid & 63;
  const int lr = lane & 15, lq = lane >> 4;
  const int h = blockIdx.y, b = blockIdx.z;
  const long rowb = (long)b * 2048;
  const int hoff = h * 128;

  const int vr = (tid & 31) * 2;
  const int vcol = (tid >> 5) * 16;

  for (int pass = 0; pass < 2; pass++) {
    const int qt = pass ? (31 - blockIdx.x) : blockIdx.x;
    const int qbase = qt * 64;
    const int nt = qt + 1;             // kv64 tiles

    s16x8 qf[4];
    {
      const short* qp = q + (rowb + qbase + wave * 16 + lr) * 2048 + hoff + lq * 8;
#pragma unroll
      for (int ks = 0; ks < 4; ks++) qf[ks] = *(const s16x8*)(qp + ks * 32);
    }
    f32x4 acc[8] = {};
    float mrun[4], lrun[4];
#pragma unroll
    for (int r = 0; r < 4; r++) { mrun[r] = -1e30f; lrun[r] = 0.f; }

    s16x8 vl[4];
    {
      const short* vp = v + (rowb + vr) * 2048 + hoff + vcol;
      vl[0] = *(const s16x8*)vp;       vl[1] = *(const s16x8*)(vp + 8);
      vl[2] = *(const s16x8*)(vp + 2048); vl[3] = *(const s16x8*)(vp + 2048 + 8);
    }
#pragma unroll
    for (int L = 0; L < 4; L++) {
      int ci = L * 256 + tid;
      int krow = ci >> 4, dslot = ci & 15;
      int col = (dslot ^ (krow & 7)) * 8;
      ASYNC16(&Ks[0][ci * 8], k + (rowb + krow) * 2048 + hoff + col);
    }
#pragma unroll
    for (int e = 0; e < 16; e++) {
      int col = vcol + e;
      unsigned pk = (unsigned)(unsigned short)vl[e >> 3][e & 7]
                  | ((unsigned)(unsigned short)vl[2 + (e >> 3)][e & 7] << 16);
      *(unsigned*)&Vt[col * 72 + vr] = pk;
    }
    __syncthreads();

    int cur = 0;
    for (int ti = 0; ti < nt; ti++) {
      const int kv0 = ti * 64;
      const bool pre = (ti + 1 < nt);
      s16x8 vn[4];
      if (pre) {
        const short* vp = v + (rowb + kv0 + 64 + vr) * 2048 + hoff + vcol;
        vn[0] = *(const s16x8*)vp;       vn[1] = *(const s16x8*)(vp + 8);
        vn[2] = *(const s16x8*)(vp + 2048); vn[3] = *(const s16x8*)(vp + 2048 + 8);
#pragma unroll
        for (int L = 0; L < 4; L++) {
          int ci = L * 256 + tid;
          int krow = ci >> 4, dslot = ci & 15;
          int col = (dslot ^ (krow & 7)) * 8;
          ASYNC16(&Ks[cur ^ 1][ci * 8], k + (rowb + kv0 + 64 + krow) * 2048 + hoff + col);
        }
      }
      f32x4 s[4] = {};
#pragma unroll
      for (int kvf = 0; kvf < 4; kvf++) {
        const int krow = kvf * 16 + lr;
#pragma unroll
        for (int ks = 0; ks < 4; ks++) {
          int doff = ks * 4 + lq;
          s16x8 kf = *(const s16x8*)&Ks[cur][krow * 128 + ((doff ^ (krow & 7)) * 8)];
          s[kvf] = mfma16(qf[ks], kf, s[kvf]);
        }
      }
      if (ti == nt - 1) {
#pragma unroll
        for (int kvf = 0; kvf < 4; kvf++) {
          int kvc = kv0 + kvf * 16 + lr;
#pragma unroll
          for (int r = 0; r < 4; r++) {
            int qr = qbase + wave * 16 + lq * 4 + r;
            if (kvc > qr) s[kvf][r] = -3.0e38f;
          }
        }
      }
      float mt[4], rs[4];
#pragma unroll
      for (int r = 0; r < 4; r++)
        mt[r] = fmaxf(fmaxf(s[0][r], s[1][r]), fmaxf(s[2][r], s[3][r]));
#pragma unroll
      for (int d = 1; d < 16; d <<= 1)
#pragma unroll
        for (int r = 0; r < 4; r++) mt[r] = fmaxf(mt[r], __shfl_xor(mt[r], d));
      int need = 0;
#pragma unroll
      for (int r = 0; r < 4; r++) need |= (mt[r] > mrun[r] + 8.f);
      if (__any(need)) {
#pragma unroll
        for (int r = 0; r < 4; r++) {
          float mn = fmaxf(mrun[r], mt[r]);
          float sf = __expf(mrun[r] - mn);
          mrun[r] = mn;
          lrun[r] *= sf;
#pragma unroll
          for (int df = 0; df < 8; df++) acc[df][r] *= sf;
        }
      }
      short* pw = &Pl[wave][0];
#pragma unroll
      for (int r = 0; r < 4; r++) rs[r] = 0.f;
#pragma unroll
      for (int kvf = 0; kvf < 4; kvf++)
#pragma unroll
        for (int r = 0; r < 4; r++) {
          float pp = __expf(s[kvf][r] - mrun[r]);
          rs[r] += pp;
          pw[(lq * 4 + r) * 72 + kvf * 16 + lr] = f2bf(pp);
        }
#pragma unroll
      for (int d = 1; d < 16; d <<= 1)
#pragma unroll
        for (int r = 0; r < 4; r++) rs[r] += __shfl_xor(rs[r], d);
#pragma unroll
      for (int r = 0; r < 4; r++) lrun[r] += rs[r];
      s16x8 pf0 = *(const s16x8*)&pw[lr * 72 + lq * 8];
      s16x8 pf1 = *(const s16x8*)&pw[lr * 72 + 32 + lq * 8];
#pragma unroll
      for (int df = 0; df < 8; df++) {
        s16x8 vf0 = *(const s16x8*)&Vt[(df * 16 + lr) * 72 + lq * 8];
        s16x8 vf1 = *(const s16x8*)&Vt[(df * 16 + lr) * 72 + 32 + lq * 8];
        acc[df] = mfma16(pf0, vf0, acc[df]);
        acc[df] = mfma16(pf1, vf1, acc[df]);
      }
      __syncthreads();
      if (pre) {
#pragma unroll
        for (int e = 0; e < 16; e++) {
          int col = vcol + e;
          unsigned pk = (unsigned)(unsigned short)vn[e >> 3][e & 7]
                      | ((unsigned)(unsigned short)vn[2 + (e >> 3)][e & 7] << 16);
          *(unsigned*)&Vt[col * 72 + vr] = pk;
        }
        __syncthreads();
      }
      cur ^= 1;
    }
#pragma unroll
    for (int r = 0; r < 4; r++) {
      float inv = 1.0f / lrun[r];
      long orow = rowb + qbase + wave * 16 + lq * 4 + r;
#pragma unroll
      for (int df = 0; df < 8; df++)
        o[orow * 2048 + hoff + df * 16 + lr] = f2bf(acc[df][r] * inv);
    }
  }
}

extern "C" void kernel_launch(void* const* d_in, const int* in_sizes, int n_in,
                              void* d_out, int out_size, void* d_ws, size_t ws_size,
                              hipStream_t stream) {
  const float* x  = (const float*)d_in[0];
  const float* Wq = (const float*)d_in[1];
  const float* Wk = (const float*)d_in[2];
  const float* Wv = (const float*)d_in[3];
  const float* Wo = (const float*)d_in[4];
  float* out = (float*)d_out;

  char* p = (char*)d_ws;
  short* xb  = (short*)p; p += 8388608L * 2;
  short* wqb = (short*)p; p += 4194304L * 2;
  short* wkb = (short*)p; p += 4194304L * 2;
  short* wvb = (short*)p; p += 4194304L * 2;
  short* wob = (short*)p; p += 4194304L * 2;
  short* qb  = (short*)p; p += 8388608L * 2;
  short* kb  = (short*)p; p += 8388608L * 2;
  short* vb  = (short*)p; p += 8388608L * 2;
  short* ab  = (short*)p; p += 8388608L * 2;
  float* cosT = (float*)p; p += 131072L * 4;
  float* sinT = (float*)p; p += 131072L * 4;

  cvt_all_k<<<24576, 256, 0, stream>>>(x, Wq, Wk, Wv, Wo, xb, wqb, wkb, wvb, wob);
  rope_tables_k<<<512, 256, 0, stream>>>(cosT, sinT);

  gemm_qkv9_k<<<dim3(24, 16), 512, 0, stream>>>(xb, wqb, wkb, wvb,
                                                qb, kb, vb, cosT, sinT);

  attn_k<<<dim3(16, 16, 2), 256, 0, stream>>>(qb, kb, vb, ab);

  gemm_out9_k<<<dim3(16, 16), 512, 0, stream>>>(ab, wob, out);
}